// Round 6
// baseline (111.172 us; speedup 1.0000x reference)
//
#include <hip/hip_runtime.h>
#include <hip/hip_bf16.h>

#define CC    32
#define HH    80
#define WW    80
#define HW    6400     // 80*80
#define HPQ   77
#define WPQ   77
#define PP    5929     // 77*77
#define DD    512      // 32*4*4
#define MSTR  81
#define NTILE 93       // ceil(PP/64) candidate blocks of 64
#define QTILES 372     // 5952/16 worst-case query tiles (also 93*4 ptiles)
#define NEGINF (-1e9f)

typedef __attribute__((ext_vector_type(4))) float f32x4;
typedef __attribute__((ext_vector_type(8))) short bf16x8;
typedef __attribute__((ext_vector_type(8))) unsigned short u16x8;

__device__ __forceinline__ void split_bf16(float v, unsigned short& hi, unsigned short& lo) {
    __hip_bfloat16 h = __float2bfloat16(v);
    float hf = __bfloat162float(h);
    __hip_bfloat16 lw = __float2bfloat16(v - hf);
    hi = *reinterpret_cast<unsigned short*>(&h);
    lo = *reinterpret_cast<unsigned short*>(&lw);
}

// ---------------- mask flags + compaction: single block ----------------
__global__ __launch_bounds__(1024) void k_mask(const int* __restrict__ mask,
                                               int* __restrict__ excl,
                                               int* __restrict__ valid,
                                               int* __restrict__ qlist,
                                               int* __restrict__ nvalid) {
    __shared__ int cnt;
    if (threadIdx.x == 0) cnt = 0;
    __syncthreads();
    for (int p = threadIdx.x; p < PP; p += 1024) {
        int pi = p / WPQ, pj = p % WPQ;
        int m00 = mask[pi * MSTR + pj];
        int m01 = mask[pi * MSTR + pj + 4];
        int m10 = mask[(pi + 4) * MSTR + pj];
        int m11 = mask[(pi + 4) * MSTR + pj + 4];
        excl[p] = (m00 == 1) ? 1 : 0;
        int v = (m00 != 0 && m01 != 0 && m10 != 0 && m11 != 0) ? 1 : 0;
        valid[p] = v;
        if (v) {
            int s = atomicAdd(&cnt, 1);
            qlist[s] = p;
        }
    }
    __syncthreads();
    if (threadIdx.x == 0) *nvalid = cnt;
}

// ---------------- pack B fused with norm: one block per ptile (16 patches) ----------------
// Pass 1: load all 16x512 elems into regs (32/thread), sum-of-squares per patch.
// LDS reduce -> invn. Pass 2: scale, split, store frags.
// frag layout: [ptile u][kstep s][lane l][j]; lane: n=l&15 (cand), k=s*32+(l>>4)*8+j
__global__ __launch_bounds__(256) void k_packBn(const float* __restrict__ low,
                                                unsigned short* __restrict__ Bhi,
                                                unsigned short* __restrict__ Blo) {
    const int u = blockIdx.x;
    const int tid = threadIdx.x;
    const int l = tid & 63, w = tid >> 6;
    const int n = l & 15, quad = l >> 4;
    const int p = u * 16 + n;
    const bool pok = (p < PP);
    const int pi = pok ? p / WPQ : 0, pj = pok ? p % WPQ : 0;
    const int pbase = pi * WW + pj;

    float v[4][8];
    float sq = 0.f;
#pragma unroll
    for (int ss = 0; ss < 4; ++ss) {
        int s = w * 4 + ss;
        int kbase = s * 32 + quad * 8;
        int base = (kbase >> 4) * HW + pbase;   // c fixed across j (kbase%16 in {0,8})
#pragma unroll
        for (int j = 0; j < 8; ++j) {
            int kk = kbase + j;
            int di = (kk >> 2) & 3, dj = kk & 3;
            float x = pok ? low[base + di * WW + dj] : 0.f;
            v[ss][j] = x;
            sq += x * x;
        }
    }
    __shared__ float part[16][17];
    __shared__ float invn_s[16];
    part[w * 4 + quad][n] = sq;
    __syncthreads();
    if (tid < 16) {
        float t = 0.f;
#pragma unroll
        for (int i = 0; i < 16; ++i) t += part[i][tid];
        invn_s[tid] = 1.0f / (sqrtf(t) + 1e-6f);
    }
    __syncthreads();
    const float sc = invn_s[n];
#pragma unroll
    for (int ss = 0; ss < 4; ++ss) {
        int s = w * 4 + ss;
        u16x8 vh, vl;
#pragma unroll
        for (int j = 0; j < 8; ++j) {
            unsigned short h, lo;
            split_bf16(v[ss][j] * sc, h, lo);
            vh[j] = h; vl[j] = lo;
        }
        int off = u * 8192 + s * 512 + l * 8;
        *reinterpret_cast<u16x8*>(Bhi + off) = vh;
        *reinterpret_cast<u16x8*>(Blo + off) = vl;
    }
}

// ---------------- pack A: high (valid queries, compacted) -> bf16 hi/lo frags ----------------
__global__ __launch_bounds__(256) void k_packA(const float* __restrict__ high,
                                               const int* __restrict__ qlist,
                                               const int* __restrict__ nvalid,
                                               unsigned short* __restrict__ Ahi,
                                               unsigned short* __restrict__ Alo) {
    int t = blockIdx.x * 256 + threadIdx.x;
    if (t >= QTILES * 16 * 64) return;
    int nv = *nvalid;
    int l = t & 63;
    int s = (t >> 6) & 15;
    int u = t >> 10;
    if ((u >> 2) * 64 >= nv) return;              // qblk inactive -> frags never read
    int m = l & 15, quad = l >> 4;
    int slot = u * 16 + m;
    int kbase = s * 32 + quad * 8;

    u16x8 vh, vl;
    if (slot < nv) {
        int q = qlist[slot];
        int qi = q / WPQ, qj = q % WPQ;
        int base = (kbase >> 4) * HW + qi * WW + qj;
#pragma unroll
        for (int j = 0; j < 8; ++j) {
            int kk = kbase + j;
            int di = (kk >> 2) & 3, dj = kk & 3;
            float v = high[base + di * WW + dj];
            unsigned short h, lo;
            split_bf16(v, h, lo);
            vh[j] = h; vl[j] = lo;
        }
    } else {
#pragma unroll
        for (int j = 0; j < 8; ++j) { vh[j] = 0; vl[j] = 0; }
    }
    int off = t * 8;
    *reinterpret_cast<u16x8*>(Ahi + off) = vh;
    *reinterpret_cast<u16x8*>(Alo + off) = vl;
}

// ---------------- score: MFMA bf16-split GEMM + argmax ----------------
// grid (93 pblk, 93 qblk), 256 thr = 4 waves; wave w: qtile qblk*4+w x 64 candidates.
__global__ __launch_bounds__(256) void k_score(const unsigned short* __restrict__ Ahi,
                                               const unsigned short* __restrict__ Alo,
                                               const unsigned short* __restrict__ Bhi,
                                               const unsigned short* __restrict__ Blo,
                                               const int* __restrict__ excl,
                                               const int* __restrict__ nvalid,
                                               float* __restrict__ pscore,
                                               int* __restrict__ pidx) {
    const int nv = *nvalid;
    const int qblk = blockIdx.y;
    if (qblk * 64 >= nv) return;
    const int pblk = blockIdx.x;
    const int w = threadIdx.x >> 6;
    const int l = threadIdx.x & 63;
    const int qtile = qblk * 4 + w;

    f32x4 acc[4];
#pragma unroll
    for (int pt = 0; pt < 4; ++pt) acc[pt] = (f32x4){0.f, 0.f, 0.f, 0.f};

    const int abase = qtile * 8192 + l * 8;       // [tile][s][lane][8]
    const int bbase0 = pblk * 4 * 8192 + l * 8;   // ptile = pblk*4+pt

#pragma unroll 4
    for (int s = 0; s < 16; ++s) {
        bf16x8 ah = *reinterpret_cast<const bf16x8*>(Ahi + abase + s * 512);
        bf16x8 al = *reinterpret_cast<const bf16x8*>(Alo + abase + s * 512);
#pragma unroll
        for (int pt = 0; pt < 4; ++pt) {
            int boff = bbase0 + pt * 8192 + s * 512;
            bf16x8 bh = *reinterpret_cast<const bf16x8*>(Bhi + boff);
            bf16x8 bl = *reinterpret_cast<const bf16x8*>(Blo + boff);
            acc[pt] = __builtin_amdgcn_mfma_f32_16x16x32_bf16(ah, bh, acc[pt], 0, 0, 0);
            acc[pt] = __builtin_amdgcn_mfma_f32_16x16x32_bf16(ah, bl, acc[pt], 0, 0, 0);
            acc[pt] = __builtin_amdgcn_mfma_f32_16x16x32_bf16(al, bh, acc[pt], 0, 0, 0);
        }
    }

    // C/D layout: col n = l&15 (candidate), row m = (l>>4)*4 + reg (query)
    const int n = l & 15, quad = l >> 4;
    float bs[4]; int bi[4];
#pragma unroll
    for (int r = 0; r < 4; ++r) { bs[r] = -3.4e38f; bi[r] = 0x7fffffff; }
#pragma unroll
    for (int pt = 0; pt < 4; ++pt) {
        int gp = pblk * 64 + pt * 16 + n;
        if (gp < PP) {
            bool ex = (excl[gp] != 0);
#pragma unroll
            for (int r = 0; r < 4; ++r) {
                float sv = ex ? NEGINF : acc[pt][r];
                if (sv > bs[r]) { bs[r] = sv; bi[r] = gp; }   // pt ascending -> lowest gp on tie
            }
        }
    }
    // reduce over the 16 lanes of this quad-row group (xor 1,2,4,8 stays in group)
#pragma unroll
    for (int off = 1; off <= 8; off <<= 1) {
#pragma unroll
        for (int r = 0; r < 4; ++r) {
            float s2 = __shfl_xor(bs[r], off, 64);
            int   i2 = __shfl_xor(bi[r], off, 64);
            if (s2 > bs[r] || (s2 == bs[r] && i2 < bi[r])) { bs[r] = s2; bi[r] = i2; }
        }
    }
    if (n == 0) {
#pragma unroll
        for (int r = 0; r < 4; ++r) {
            int slot = qtile * 16 + quad * 4 + r;
            pscore[slot * NTILE + pblk] = bs[r];
            pidx[slot * NTILE + pblk] = bi[r];
        }
    }
}

// ---------------- reduce partials -> best[q]: one block (64 thr) per slot ----------------
__global__ __launch_bounds__(64) void k_reduce(const float* __restrict__ pscore,
                                               const int* __restrict__ pidx,
                                               const int* __restrict__ qlist,
                                               const int* __restrict__ nvalid,
                                               int* __restrict__ best) {
    const int slot = blockIdx.x;
    if (slot >= *nvalid) return;
    const int t = threadIdx.x;
    float bs = -3.4e38f;
    int bi = 0x7fffffff;
    for (int k = t; k < NTILE; k += 64) {
        float s = pscore[slot * NTILE + k];
        int i = pidx[slot * NTILE + k];
        if (s > bs || (s == bs && i < bi)) { bs = s; bi = i; }
    }
#pragma unroll
    for (int off = 32; off >= 1; off >>= 1) {
        float s2 = __shfl_down(bs, off);
        int   i2 = __shfl_down(bi, off);
        if (s2 > bs || (s2 == bs && i2 < bi)) { bs = s2; bi = i2; }
    }
    if (t == 0) best[qlist[slot]] = bi;
}

// ---------------- prep: per-pixel count + source-offset list (c-independent) ----------------
__global__ __launch_bounds__(256) void k_prep(const int* __restrict__ best,
                                              const int* __restrict__ valid,
                                              int* __restrict__ cnt,
                                              int* __restrict__ offlist) {
    int pix = blockIdx.x * 256 + threadIdx.x;
    if (pix >= HW) return;
    int i = pix / WW, j = pix % WW;
    int n = 0;
#pragma unroll
    for (int di = 0; di < 4; ++di) {
        int qi = i - di;
        if (qi < 0 || qi >= HPQ) continue;
#pragma unroll
        for (int dj = 0; dj < 4; ++dj) {
            int qj = j - dj;
            if (qj < 0 || qj >= WPQ) continue;
            int q = qi * WPQ + qj;
            if (valid[q]) {
                int b = best[q];
                int bi = b / WPQ, bj = b % WPQ;
                offlist[pix * 16 + n] = (bi + di) * WW + (bj + dj);
                n++;
            }
        }
    }
    cnt[pix] = n;
}

// ---------------- gather + overlap-add + normalize ----------------
__global__ __launch_bounds__(256) void k_out(const float* __restrict__ low,
                                             const int* __restrict__ cnt,
                                             const int* __restrict__ offlist,
                                             float* __restrict__ out) {
    int idx = blockIdx.x * 256 + threadIdx.x;
    if (idx >= CC * HW) return;
    int c = idx / HW;
    int pix = idx % HW;
    int n = cnt[pix];
    if (n > 0) {
        int base = c * HW;
        float acc = 0.f;
        for (int t = 0; t < n; ++t)
            acc += low[base + offlist[pix * 16 + t]];
        out[idx] = acc / ((float)n + 1e-6f);
    } else {
        out[idx] = low[idx];
    }
}

extern "C" void kernel_launch(void* const* d_in, const int* in_sizes, int n_in,
                              void* d_out, int out_size, void* d_ws, size_t ws_size,
                              hipStream_t stream) {
    const float* low  = (const float*)d_in[0];
    const float* high = (const float*)d_in[1];
    const int*   mask = (const int*)d_in[2];
    float* out = (float*)d_out;

    char* ws = (char*)d_ws;
    int*   nvalid = (int*)(ws);                         // 64 B
    int*   qlist  = (int*)(ws + 64);                    // 24,000
    int*   excl   = (int*)(ws + 24064);
    int*   valid  = (int*)(ws + 48128);
    int*   best   = (int*)(ws + 72192);
    float* pscore = (float*)(ws + 96256);               // 5952*93*4 = 2,214,144
    int*   pidx   = (int*)(ws + 2310400);               // 2,214,144
    int*   cnt    = (int*)(ws + 4524544);               // 25,600
    int*   offlist= (int*)(ws + 4550144);               // 409,600
    unsigned short* Ahi = (unsigned short*)(ws + 4959744);   // 6,094,848 each
    unsigned short* Alo = (unsigned short*)(ws + 11054592);
    unsigned short* Bhi = (unsigned short*)(ws + 17149440);
    unsigned short* Blo = (unsigned short*)(ws + 23244288);  // end ~29.3 MB

    hipLaunchKernelGGL(k_mask, dim3(1), dim3(1024), 0, stream,
                       mask, excl, valid, qlist, nvalid);
    hipLaunchKernelGGL(k_packBn, dim3(QTILES), dim3(256), 0, stream,
                       low, Bhi, Blo);
    hipLaunchKernelGGL(k_packA, dim3(QTILES * 4), dim3(256), 0, stream,
                       high, qlist, nvalid, Ahi, Alo);
    hipLaunchKernelGGL(k_score, dim3(NTILE, 93), dim3(256), 0, stream,
                       Ahi, Alo, Bhi, Blo, excl, nvalid, pscore, pidx);
    hipLaunchKernelGGL(k_reduce, dim3(5952), dim3(64), 0, stream,
                       pscore, pidx, qlist, nvalid, best);
    hipLaunchKernelGGL(k_prep, dim3((HW + 255) / 256), dim3(256), 0, stream,
                       best, valid, cnt, offlist);
    hipLaunchKernelGGL(k_out, dim3((CC * HW + 255) / 256), dim3(256), 0, stream,
                       low, cnt, offlist, out);
}